// Round 5
// baseline (536.694 us; speedup 1.0000x reference)
//
#include <hip/hip_runtime.h>
#include <hip/hip_bf16.h>
#include <hip/hip_fp16.h>

#define MPTS 200000
#define NCAM 6
#define CIMG 96
#define HF 32
#define WF 88
#define PDIM 128
#define FDIM 224
#define FDIM_P 232            // LDS row pad: dword stride 116 ≡ 20 (mod 32) → 2-way max (free)
#define ORIH 256
#define ORIW 704
#define GZD 32
#define GYD 512
#define GXD 448
#define NCELLS (GZD*GYD*GXD)
#define PAIR_CAP 16384
#define CAP2 8192             // pairout rows per k (cnt[k] ~5.5K max, 8192 is safe)
#define IID_CAP 12            // max neighbor entries per point (Poisson λ≈0.7 → P(>12)~1e-14)
#define BN_EPS 1e-5f
#define TROWS 64              // GEMM tile rows (pairs/points per block)

// ---- workspace layout (bytes), all offsets 16B-aligned ----
#define OFF_GRID   0UL            // int[NCELLS]            29,360,128 B
#define OFF_IMGT   29360128UL     // bf16[6*32*88*96]        3,244,032 B
#define OFF_DESCM  35848192UL     // uint[M*6]               4,800,000 B  (sample meta)
#define OFF_WPACK  OFF_DESCM      //                         1,548,288 B  (overlays desc_meta AFTER k_fuse_img)
#define OFF_DESCW  40648192UL     // uint2[M*6]              9,600,000 B  (f16 corner weights)
#define OFF_FUSE   50248192UL     // bf16[M*224]            89,600,000 B
#define OFF_CNT    139848192UL    // int[32]
#define OFF_PAIRS  139848320UL    // int2[27*PAIR_CAP]       3,538,944 B
// ---- extended region (only used when ws_size permits) ----
#define OFF_ICNT   143387264UL    // int[M]                    800,000 B
#define OFF_IIDX   144187264UL    // int[M*12]               9,600,000 B
#define OFF_POUT   153787264UL    // f32[26*CAP2*128]      109,051,904 B
#define WS_NEED_BIG 262839168UL

#define BPTS (MPTS*8/256)         // 6250 blocks: pts copy (M*8 threads, 4 float4 each)
#define BIMG (MPTS*12/256)        // 9375 blocks: img sample (M*12 threads, 8ch quads)

typedef __attribute__((ext_vector_type(8))) short bf16x8;
typedef __attribute__((ext_vector_type(4))) float f32x4;

__device__ __forceinline__ unsigned short f32_to_bf16bits(float f) {
    __hip_bfloat16 h = __float2bfloat16(f);   // RNE
    return *reinterpret_cast<unsigned short*>(&h);
}

__device__ __forceinline__ float bf16bits_to_f32(unsigned short u) {
    return __uint_as_float(((unsigned int)u) << 16);
}

__device__ __forceinline__ ushort4 cvt4(float4 v) {
    ushort4 o;
    o.x = f32_to_bf16bits(v.x); o.y = f32_to_bf16bits(v.y);
    o.z = f32_to_bf16bits(v.z); o.w = f32_to_bf16bits(v.w);
    return o;
}

// ------- transpose img (cam,C,H,W) f32 -> (cam,H,W,C) bf16 for coalesced gathers
__global__ __launch_bounds__(256) void k_transpose(const float* __restrict__ img,
                                                   unsigned short* __restrict__ imgt) {
    int tid = blockIdx.x * 256 + threadIdx.x;
    if (tid >= NCAM*CIMG*HF*WF) return;
    int c = tid % CIMG;
    int r = tid / CIMG;
    int x = r % WF;
    int r2 = r / WF;
    int y = r2 % HF;
    int cam = r2 / HF;
    imgt[tid] = f32_to_bf16bits(img[((cam*CIMG + c)*HF + y)*WF + x]);
}

// ------- projection + bilinear setup + grid scatter ---------------------------
__global__ __launch_bounds__(256) void k_proj(const int* __restrict__ vc,
                                              const float* __restrict__ l2i,
                                              const float* __restrict__ iaug,
                                              const float* __restrict__ laug,
                                              int* __restrict__ grid,
                                              unsigned int* __restrict__ meta,
                                              uint2* __restrict__ wts) {
    int i = blockIdx.x * 256 + threadIdx.x;
    if (i >= MPTS) return;
    int cz = vc[i*4+1], cy = vc[i*4+2], cx = vc[i*4+3];
    atomicMax(&grid[(cz*GYD + cy)*GXD + cx], i);
    float cxf = (float)cx, cyf = (float)cy, czf = (float)cz;
    float a00=laug[0],a01=laug[1],a02=laug[2];
    float a10=laug[4],a11=laug[5],a12=laug[6];
    float a20=laug[8],a21=laug[9],a22=laug[10];
    float t0=laug[3], t1=laug[7], t2=laug[11];
    float det = a00*(a11*a22-a12*a21) - a01*(a10*a22-a12*a20) + a02*(a10*a21-a11*a20);
    float id = 1.0f/det;
    float b00 =  (a11*a22-a12*a21)*id, b01 = -(a01*a22-a02*a21)*id, b02 =  (a01*a12-a02*a11)*id;
    float b10 = -(a10*a22-a12*a20)*id, b11 =  (a00*a22-a02*a20)*id, b12 = -(a00*a12-a02*a10)*id;
    float b20 =  (a10*a21-a11*a20)*id, b21 = -(a00*a21-a01*a20)*id, b22 =  (a00*a11-a01*a10)*id;
    float px = cxf-t0, py = cyf-t1, pz = czf-t2;
    float X = b00*px + b01*py + b02*pz;
    float Y = b10*px + b11*py + b12*pz;
    float Z = b20*px + b21*py + b22*pz;
    #pragma unroll
    for (int cam = 0; cam < NCAM; cam++) {
        const float* Lm = l2i + cam*16;
        float c0 = Lm[0]*X + Lm[1]*Y + Lm[2]*Z  + Lm[3];
        float c1 = Lm[4]*X + Lm[5]*Y + Lm[6]*Z  + Lm[7];
        float c2 = Lm[8]*X + Lm[9]*Y + Lm[10]*Z + Lm[11];
        float z  = fminf(fmaxf(c2, 1e-5f), 100000.0f);
        float vx = c0/z, vy = c1/z, vz = z;
        const float* Am = iaug + cam*16;
        float d0 = Am[0]*vx + Am[1]*vy + Am[2]*vz + Am[3];
        float d1 = Am[4]*vx + Am[5]*vy + Am[6]*vz + Am[7];
        float x = d0 * ((float)(WF-1)/(float)ORIW);
        float y = d1 * ((float)(HF-1)/(float)ORIH);
        bool act = (x > -1.0f) && (x < (float)WF) && (y > -1.0f) && (y < (float)HF);
        float x0f = floorf(x), y0f = floorf(y);
        int x0 = (int)x0f, y0 = (int)y0f;
        float wx1 = x - x0f, wy1 = y - y0f;
        float wx0 = 1.f - wx1, wy0 = 1.f - wy1;
        float ux0, ux1, uy0, uy1;
        if (x0 < 0)            { ux0 = wx1; ux1 = 0.f; }
        else if (x0 >= WF-1)   { ux0 = 0.f; ux1 = wx0; }
        else                   { ux0 = wx0; ux1 = wx1; }
        if (y0 < 0)            { uy0 = wy1; uy1 = 0.f; }
        else if (y0 >= HF-1)   { uy0 = 0.f; uy1 = wy0; }
        else                   { uy0 = wy0; uy1 = wy1; }
        int xb = min(max(x0, 0), WF-2);
        int yb = min(max(y0, 0), HF-2);
        unsigned int m = 0u;
        __half2 h01 = __floats2half2_rn(0.f, 0.f), h23 = h01;
        if (act) {
            m = 0x8000u | (unsigned int)(yb*WF + xb);
            h01 = __floats2half2_rn(ux0*uy0, ux1*uy0);
            h23 = __floats2half2_rn(ux0*uy1, ux1*uy1);
        }
        meta[i*6 + cam] = m;
        uint2 wv;
        wv.x = *reinterpret_cast<unsigned int*>(&h01);
        wv.y = *reinterpret_cast<unsigned int*>(&h23);
        wts[i*6 + cam] = wv;
    }
}

// ------- fuse pts half: stream pts f32 -> bf16 into fuse rows ----------------
__global__ __launch_bounds__(256) void k_fuse_pts(const float4* __restrict__ pts4,
                                                  ushort4* __restrict__ fuse4) {
    int t = blockIdx.x*256 + threadIdx.x;        // t over M*8
    int i = t >> 3, c = t & 7;
    float4 v0 = pts4[i*32 + c];
    float4 v1 = pts4[i*32 + c + 8];
    float4 v2 = pts4[i*32 + c + 16];
    float4 v3 = pts4[i*32 + c + 24];
    fuse4[i*56 + c]      = cvt4(v0);
    fuse4[i*56 + c + 8]  = cvt4(v1);
    fuse4[i*56 + c + 16] = cvt4(v2);
    fuse4[i*56 + c + 24] = cvt4(v3);
}

// ------- fuse img half: bilinear gather from bf16 imgt, 8 channels/thread -----
__global__ __launch_bounds__(256) void k_fuse_img(const uint4* __restrict__ imgt16,
                                                  const unsigned int* __restrict__ meta,
                                                  const uint2* __restrict__ wts,
                                                  uint4* __restrict__ fuse16o) {
    int t = blockIdx.x*256 + threadIdx.x;        // t over M*12
    int i = t / 12, sg = t % 12;
    unsigned int m[NCAM]; uint2 w[NCAM];
    #pragma unroll
    for (int cam = 0; cam < NCAM; cam++) { m[cam] = meta[i*6+cam]; w[cam] = wts[i*6+cam]; }
    float acc[8] = {0.f,0.f,0.f,0.f,0.f,0.f,0.f,0.f};
    #pragma unroll
    for (int cam = 0; cam < NCAM; cam++) {
        if (m[cam] & 0x8000u) {
            int pix = (int)(m[cam] & 0x1FFFu);
            const uint4* base = imgt16 + (size_t)cam*(HF*WF*(CIMG/8)) + (size_t)pix*(CIMG/8) + sg;
            uint4 t00 = base[0];
            uint4 t01 = base[(CIMG/8)];
            uint4 t10 = base[WF*(CIMG/8)];
            uint4 t11 = base[(WF+1)*(CIMG/8)];
            float2 w01 = __half22float2(*reinterpret_cast<const __half2*>(&w[cam].x));
            float2 w23 = __half22float2(*reinterpret_cast<const __half2*>(&w[cam].y));
            const unsigned short* s00 = reinterpret_cast<const unsigned short*>(&t00);
            const unsigned short* s01 = reinterpret_cast<const unsigned short*>(&t01);
            const unsigned short* s10 = reinterpret_cast<const unsigned short*>(&t10);
            const unsigned short* s11 = reinterpret_cast<const unsigned short*>(&t11);
            #pragma unroll
            for (int ch = 0; ch < 8; ch++) {
                acc[ch] += bf16bits_to_f32(s00[ch])*w01.x + bf16bits_to_f32(s01[ch])*w01.y
                         + bf16bits_to_f32(s10[ch])*w23.x + bf16bits_to_f32(s11[ch])*w23.y;
            }
        }
    }
    unsigned int o0 = (unsigned int)f32_to_bf16bits(acc[0]) | ((unsigned int)f32_to_bf16bits(acc[1]) << 16);
    unsigned int o1 = (unsigned int)f32_to_bf16bits(acc[2]) | ((unsigned int)f32_to_bf16bits(acc[3]) << 16);
    unsigned int o2 = (unsigned int)f32_to_bf16bits(acc[4]) | ((unsigned int)f32_to_bf16bits(acc[5]) << 16);
    unsigned int o3 = (unsigned int)f32_to_bf16bits(acc[6]) | ((unsigned int)f32_to_bf16bits(acc[7]) << 16);
    fuse16o[(size_t)i*28 + 16 + sg] = make_uint4(o0, o1, o2, o3);
}

// ---------------- pack conv_w into bf16 MFMA B-fragment layout ----------------
__global__ __launch_bounds__(256) void k_wpack(const float* __restrict__ conv,
                                               ushort4* __restrict__ wp) {
    int tid = blockIdx.x * 256 + threadIdx.x;
    if (tid >= 27*7*8*64) return;
    int lane = tid & 63;
    int nt   = (tid >> 6) & 7;
    int kk   = (tid >> 9) % 7;
    int k27  = tid / 3584;
    int n     = nt*16 + (lane & 15);
    int kbase = kk*32 + (lane >> 4)*8;
    const float* src = conv + ((size_t)k27*FDIM + kbase)*PDIM + n;
    ushort4 lo, hi;
    lo.x = f32_to_bf16bits(src[0*PDIM]);
    lo.y = f32_to_bf16bits(src[1*PDIM]);
    lo.z = f32_to_bf16bits(src[2*PDIM]);
    lo.w = f32_to_bf16bits(src[3*PDIM]);
    hi.x = f32_to_bf16bits(src[4*PDIM]);
    hi.y = f32_to_bf16bits(src[5*PDIM]);
    hi.z = f32_to_bf16bits(src[6*PDIM]);
    hi.w = f32_to_bf16bits(src[7*PDIM]);
    wp[tid*2]   = lo;
    wp[tid*2+1] = hi;
}

// ---------------- pair lists, ballot-aggregated; optional per-i index ---------
__global__ __launch_bounds__(256) void k_pairs(const int* __restrict__ vc,
                                               const int* __restrict__ grid,
                                               int* __restrict__ cnt,
                                               int2* __restrict__ pairs,
                                               int* __restrict__ icnt,
                                               int* __restrict__ iidx,
                                               int build) {
    int i = blockIdx.x * 256 + threadIdx.x;
    bool act = (i < MPTS);
    int cz = 0, cy = 0, cx = 0;
    if (act) { cz = vc[i*4+1]; cy = vc[i*4+2]; cx = vc[i*4+3]; }
    __shared__ int s_wcnt[4][27];
    __shared__ int s_wbase[4][27];
    int wv = threadIdx.x >> 6, ln = threadIdx.x & 63;
    int nid[27];
    int rnk[27];
    #pragma unroll
    for (int k = 0; k < 27; k++) {
        if (k == 13) continue;
        int dz = k/9 - 1, dy = (k/3)%3 - 1, dx = k%3 - 1;
        int nz = cz+dz, ny = cy+dy, nx = cx+dx;
        int id = -1;
        if (act && nz >= 0 && nz < GZD && ny >= 0 && ny < GYD && nx >= 0 && nx < GXD)
            id = grid[(nz*GYD + ny)*GXD + nx];
        nid[k] = id;
        unsigned long long mm = __ballot(id >= 0);
        if (ln == 0) s_wcnt[wv][k] = __popcll(mm);
        rnk[k] = __popcll(mm & ((1ull << ln) - 1ull));
    }
    __syncthreads();
    if (threadIdx.x < 27 && threadIdx.x != 13) {
        int k = threadIdx.x;
        int c0 = s_wcnt[0][k], c1 = s_wcnt[1][k], c2 = s_wcnt[2][k], c3 = s_wcnt[3][k];
        int tot = c0 + c1 + c2 + c3;
        int bse = (tot > 0) ? atomicAdd(&cnt[k], tot) : 0;
        s_wbase[0][k] = bse;
        s_wbase[1][k] = bse + c0;
        s_wbase[2][k] = bse + c0 + c1;
        s_wbase[3][k] = bse + c0 + c1 + c2;
    }
    __syncthreads();
    #pragma unroll
    for (int k = 0; k < 27; k++) {
        if (k == 13) continue;
        if (nid[k] >= 0) {
            int slot = s_wbase[wv][k] + rnk[k];
            if (slot < PAIR_CAP) pairs[k*PAIR_CAP + slot] = make_int2(i, nid[k]);
            if (build && slot < CAP2) {
                int pos = atomicAdd(&icnt[i], 1);
                if (pos < IID_CAP)
                    iidx[(size_t)i*IID_CAP + pos] = ((k > 13) ? (k-1) : k)*CAP2 + slot;
            }
        }
    }
}

// ---- MFMA micro-kernel pieces (64-row tiles) --------------------------------
__device__ __forceinline__ void fill_tile64(unsigned short (*s_fb)[FDIM_P],
                                            const int* s_j,
                                            const uint4* __restrict__ fuse16,
                                            int tid) {
    #pragma unroll
    for (int it = 0; it < (TROWS*28)/256; it++) {
        int idx = it*256 + tid;
        int r = idx / 28, c = idx % 28;
        int j = s_j[r];
        uint4 v = make_uint4(0u, 0u, 0u, 0u);
        if (j >= 0) v = fuse16[(size_t)j*28 + c];
        *reinterpret_cast<uint4*>(&s_fb[r][c*8]) = v;
    }
}

__device__ __forceinline__ void gemm_mfma64(const unsigned short (*s_fb)[FDIM_P],
                                            const bf16x8* __restrict__ wpb,
                                            int k27, int lane, int wv,
                                            f32x4 acc[4][2]) {
    int quad = lane >> 4, l15 = lane & 15;
    bf16x8 b[7][2];
    #pragma unroll
    for (int kk = 0; kk < 7; kk++) {
        b[kk][0] = wpb[(((k27*7 + kk)*8) + wv*2 + 0)*64 + lane];
        b[kk][1] = wpb[(((k27*7 + kk)*8) + wv*2 + 1)*64 + lane];
    }
    #pragma unroll
    for (int kk = 0; kk < 7; kk++) {
        #pragma unroll
        for (int mt = 0; mt < 4; mt++) {
            bf16x8 a = *reinterpret_cast<const bf16x8*>(&s_fb[mt*16 + l15][kk*32 + quad*8]);
            acc[mt][0] = __builtin_amdgcn_mfma_f32_16x16x32_bf16(a, b[kk][0], acc[mt][0], 0, 0, 0);
            acc[mt][1] = __builtin_amdgcn_mfma_f32_16x16x32_bf16(a, b[kk][1], acc[mt][1], 0, 0, 0);
        }
    }
}

// ------- neighbor GEMMs, BIG path: plain coalesced row stores (no atomics) ----
__global__ __launch_bounds__(256) void k_nbr_store(const int2* __restrict__ pairs,
                                                   const int* __restrict__ cnt,
                                                   const uint4* __restrict__ fuse16,
                                                   const bf16x8* __restrict__ wpb,
                                                   float* __restrict__ pout) {
    int k26 = blockIdx.y;
    int k = (k26 >= 13) ? k26 + 1 : k26;
    int n = cnt[k];
    if (n > CAP2) n = CAP2;
    int p0 = blockIdx.x * TROWS;
    if (p0 >= n) return;
    int nn = min(TROWS, n - p0);

    __shared__ int s_j[TROWS];
    __shared__ unsigned short s_fb[TROWS][FDIM_P];
    int tid = threadIdx.x;
    if (tid < TROWS) {
        s_j[tid] = (tid < nn) ? pairs[k*PAIR_CAP + p0 + tid].y : -1;
    }
    __syncthreads();
    fill_tile64(s_fb, s_j, fuse16, tid);
    __syncthreads();

    int lane = tid & 63, wv = tid >> 6;
    int quad = lane >> 4, l15 = lane & 15;
    f32x4 acc[4][2] = {};
    gemm_mfma64(s_fb, wpb, k, lane, wv, acc);

    #pragma unroll
    for (int nt = 0; nt < 2; nt++) {
        int col = wv*32 + nt*16 + l15;
        #pragma unroll
        for (int mt = 0; mt < 4; mt++) {
            #pragma unroll
            for (int r = 0; r < 4; r++) {
                int row = mt*16 + quad*4 + r;
                pout[(size_t)(k26*CAP2 + p0 + row)*PDIM + col] = acc[mt][nt][r];
            }
        }
    }
}

// ------- center GEMM + pairout gather-sum + BN + ReLU, pure store (BIG path) --
__global__ __launch_bounds__(256) void k_center_gather(const int* __restrict__ vc,
                                                       const int* __restrict__ grid,
                                                       const uint4* __restrict__ fuse16,
                                                       const bf16x8* __restrict__ wpb,
                                                       const int* __restrict__ icnt,
                                                       const int* __restrict__ iidx,
                                                       const float* __restrict__ pout,
                                                       const float* __restrict__ gamma,
                                                       const float* __restrict__ beta,
                                                       const float* __restrict__ mean,
                                                       const float* __restrict__ var,
                                                       float* __restrict__ out) {
    int i0 = blockIdx.x * TROWS;
    __shared__ int s_j[TROWS];
    __shared__ int s_cnt[TROWS];
    __shared__ int s_idx[TROWS][IID_CAP];
    __shared__ unsigned short s_fb[TROWS][FDIM_P];
    int tid = threadIdx.x;
    if (tid < TROWS) {
        int i = i0 + tid;
        int cz = vc[i*4+1], cy = vc[i*4+2], cx = vc[i*4+3];
        s_j[tid] = grid[(cz*GYD + cy)*GXD + cx];
        s_cnt[tid] = min(icnt[i], IID_CAP);
    }
    for (int e = tid; e < TROWS*IID_CAP; e += 256) {
        int r = e / IID_CAP, q = e % IID_CAP;
        s_idx[r][q] = iidx[(size_t)(i0 + r)*IID_CAP + q];
    }
    __syncthreads();
    fill_tile64(s_fb, s_j, fuse16, tid);
    __syncthreads();

    int lane = tid & 63, wv = tid >> 6;
    int quad = lane >> 4, l15 = lane & 15;
    f32x4 acc[4][2] = {};
    gemm_mfma64(s_fb, wpb, 13, lane, wv, acc);

    #pragma unroll
    for (int nt = 0; nt < 2; nt++) {
        int col = wv*32 + nt*16 + l15;
        float g  = gamma[col], bb = beta[col], mn = mean[col];
        float rs = rsqrtf(var[col] + BN_EPS);
        #pragma unroll
        for (int mt = 0; mt < 4; mt++) {
            #pragma unroll
            for (int r = 0; r < 4; r++) {
                int row = mt*16 + quad*4 + r;
                float v = acc[mt][nt][r];
                int c = s_cnt[row];
                for (int e = 0; e < c; e++) {
                    int idx = s_idx[row][e];
                    v += pout[(size_t)idx*PDIM + col];
                }
                v = (v - mn)*rs*g + bb;
                out[(size_t)(i0 + row)*PDIM + col] = fmaxf(v, 0.f);
            }
        }
    }
}

// ------- FALLBACK path (small ws): original atomic scatter + RMW center -------
__global__ __launch_bounds__(256) void k_nbr(const int2* __restrict__ pairs,
                                             const int* __restrict__ cnt,
                                             const uint4* __restrict__ fuse16,
                                             const bf16x8* __restrict__ wpb,
                                             float* __restrict__ out) {
    int k = blockIdx.y;
    if (k >= 13) k += 1;
    int n = cnt[k];
    if (n > PAIR_CAP) n = PAIR_CAP;
    int p0 = blockIdx.x * TROWS;
    if (p0 >= n) return;
    int nn = min(TROWS, n - p0);

    __shared__ int s_i[TROWS];
    __shared__ int s_j[TROWS];
    __shared__ unsigned short s_fb[TROWS][FDIM_P];
    int tid = threadIdx.x;
    if (tid < TROWS) {
        if (tid < nn) { int2 pr = pairs[k*PAIR_CAP + p0 + tid]; s_i[tid] = pr.x; s_j[tid] = pr.y; }
        else          { s_i[tid] = -1; s_j[tid] = -1; }
    }
    __syncthreads();
    fill_tile64(s_fb, s_j, fuse16, tid);
    __syncthreads();

    int lane = tid & 63, wv = tid >> 6;
    int quad = lane >> 4, l15 = lane & 15;
    f32x4 acc[4][2] = {};
    gemm_mfma64(s_fb, wpb, k, lane, wv, acc);

    #pragma unroll
    for (int nt = 0; nt < 2; nt++) {
        int col = wv*32 + nt*16 + l15;
        #pragma unroll
        for (int mt = 0; mt < 4; mt++) {
            #pragma unroll
            for (int r = 0; r < 4; r++) {
                int row = mt*16 + quad*4 + r;
                int ii = s_i[row];
                if (ii >= 0) unsafeAtomicAdd(&out[(size_t)ii*PDIM + col], acc[mt][nt][r]);
            }
        }
    }
}

__global__ __launch_bounds__(256) void k_center(const int* __restrict__ vc,
                                                const int* __restrict__ grid,
                                                const uint4* __restrict__ fuse16,
                                                const bf16x8* __restrict__ wpb,
                                                const float* __restrict__ gamma,
                                                const float* __restrict__ beta,
                                                const float* __restrict__ mean,
                                                const float* __restrict__ var,
                                                float* __restrict__ out) {
    int i0 = blockIdx.x * TROWS;
    __shared__ int s_j[TROWS];
    __shared__ unsigned short s_fb[TROWS][FDIM_P];
    int tid = threadIdx.x;
    if (tid < TROWS) {
        int i = i0 + tid;
        int cz = vc[i*4+1], cy = vc[i*4+2], cx = vc[i*4+3];
        s_j[tid] = grid[(cz*GYD + cy)*GXD + cx];
    }
    __syncthreads();
    fill_tile64(s_fb, s_j, fuse16, tid);
    __syncthreads();

    int lane = tid & 63, wv = tid >> 6;
    int quad = lane >> 4, l15 = lane & 15;
    f32x4 acc[4][2] = {};
    gemm_mfma64(s_fb, wpb, 13, lane, wv, acc);

    #pragma unroll
    for (int nt = 0; nt < 2; nt++) {
        int col = wv*32 + nt*16 + l15;
        float g  = gamma[col], bb = beta[col], mn = mean[col];
        float rs = rsqrtf(var[col] + BN_EPS);
        #pragma unroll
        for (int mt = 0; mt < 4; mt++) {
            #pragma unroll
            for (int r = 0; r < 4; r++) {
                int row = mt*16 + quad*4 + r;
                size_t o = (size_t)(i0 + row)*PDIM + col;
                float v = out[o] + acc[mt][nt][r];
                v = (v - mn)*rs*g + bb;
                out[o] = fmaxf(v, 0.f);
            }
        }
    }
}

extern "C" void kernel_launch(void* const* d_in, const int* in_sizes, int n_in,
                              void* d_out, int out_size, void* d_ws, size_t ws_size,
                              hipStream_t stream) {
    const float* pts   = (const float*)d_in[0];
    const int*   vc    = (const int*)d_in[1];
    const float* img   = (const float*)d_in[2];
    const float* l2i   = (const float*)d_in[3];
    const float* iaug  = (const float*)d_in[4];
    const float* laug  = (const float*)d_in[5];
    const float* conv  = (const float*)d_in[6];
    const float* gamma = (const float*)d_in[7];
    const float* beta  = (const float*)d_in[8];
    const float* mean  = (const float*)d_in[9];
    const float* var   = (const float*)d_in[10];
    float* out = (float*)d_out;

    char* ws = (char*)d_ws;
    int*            grid  = (int*)(ws + OFF_GRID);
    unsigned short* imgt  = (unsigned short*)(ws + OFF_IMGT);
    unsigned int*   descm = (unsigned int*)(ws + OFF_DESCM);
    uint2*          descw = (uint2*)(ws + OFF_DESCW);
    ushort4*        wp    = (ushort4*)(ws + OFF_WPACK);   // overlays descm AFTER k_fuse_img
    ushort4*        fuse4 = (ushort4*)(ws + OFF_FUSE);
    int*            cnt   = (int*)(ws + OFF_CNT);
    int2*           pairs = (int2*)(ws + OFF_PAIRS);
    int*            icnt  = (int*)(ws + OFF_ICNT);
    int*            iidx  = (int*)(ws + OFF_IIDX);
    float*          pout  = (float*)(ws + OFF_POUT);
    const uint4*    fuse16 = (const uint4*)fuse4;
    uint4*          fuse16o = (uint4*)fuse4;
    const bf16x8*   wpb    = (const bf16x8*)wp;

    const bool big = (ws_size >= WS_NEED_BIG);

    hipMemsetAsync(grid, 0xFF, (size_t)NCELLS*4, stream);
    hipMemsetAsync(cnt, 0, 32*4, stream);
    if (big) hipMemsetAsync(icnt, 0, (size_t)MPTS*4, stream);
    else     hipMemsetAsync(d_out, 0, (size_t)out_size*4, stream);

    int blocksM = (MPTS + 255)/256;
    k_transpose<<<(NCAM*CIMG*HF*WF + 255)/256, 256, 0, stream>>>(img, imgt);
    k_proj<<<blocksM, 256, 0, stream>>>(vc, l2i, iaug, laug, grid, descm, descw);
    k_fuse_pts<<<BPTS, 256, 0, stream>>>((const float4*)pts, fuse4);
    k_fuse_img<<<BIMG, 256, 0, stream>>>((const uint4*)imgt, descm, descw, fuse16o);
    k_wpack<<<(27*7*8*64 + 255)/256, 256, 0, stream>>>(conv, wp);   // after k_fuse_img (descm overlay)
    k_pairs<<<blocksM, 256, 0, stream>>>(vc, grid, cnt, pairs, icnt, iidx, big ? 1 : 0);
    if (big) {
        k_nbr_store<<<dim3(CAP2/TROWS, 26), 256, 0, stream>>>(pairs, cnt, fuse16, wpb, pout);
        k_center_gather<<<MPTS/TROWS, 256, 0, stream>>>(vc, grid, fuse16, wpb,
                                                        icnt, iidx, pout,
                                                        gamma, beta, mean, var, out);
    } else {
        k_nbr<<<dim3(PAIR_CAP/TROWS, 26), 256, 0, stream>>>(pairs, cnt, fuse16, wpb, out);
        k_center<<<MPTS/TROWS, 256, 0, stream>>>(vc, grid, fuse16, wpb,
                                                 gamma, beta, mean, var, out);
    }
}

// Round 7
// 521.879 us; speedup vs baseline: 1.0284x; 1.0284x over previous
//
#include <hip/hip_runtime.h>
#include <hip/hip_bf16.h>
#include <hip/hip_fp16.h>

#define MPTS 200000
#define NCAM 6
#define CIMG 96
#define HF 32
#define WF 88
#define PDIM 128
#define FDIM 224
#define FDIM_P 232            // LDS row pad: dword stride 116 ≡ 20 (mod 32) → 2-way max (free)
#define ORIH 256
#define ORIW 704
#define GZD 32
#define GYD 512
#define GXD 448
#define NCELLS (GZD*GYD*GXD)
#define BN_EPS 1e-5f
#define TROWS 64              // points per k_conv tile

// ---- workspace layout (bytes), all offsets 16B-aligned ----
#define OFF_GRID   0UL            // int[NCELLS]            29,360,128 B
#define OFF_IMGT   29360128UL     // bf16[6*32*88*96]        3,244,032 B
#define OFF_DESCM  35848192UL     // uint[M*6]               4,800,000 B  (sample meta)
#define OFF_WPACK  OFF_DESCM      //                         1,548,288 B  (overlays desc_meta AFTER k_fuse_img)
#define OFF_DESCW  40648192UL     // uint2[M*6]              9,600,000 B  (f16 corner weights)
#define OFF_FUSE   50248192UL     // bf16[M*224]            89,600,000 B
// total 139,848,192 B

#define BPTS (MPTS*8/256)         // 6250 blocks: pts copy (M*8 threads, 4 float4 each)
#define BIMG (MPTS*12/256)        // 9375 blocks: img sample (M*12 threads, 8ch quads)

typedef __attribute__((ext_vector_type(8))) short bf16x8;
typedef __attribute__((ext_vector_type(4))) float f32x4;

__device__ __forceinline__ unsigned short f32_to_bf16bits(float f) {
    __hip_bfloat16 h = __float2bfloat16(f);   // RNE
    return *reinterpret_cast<unsigned short*>(&h);
}

__device__ __forceinline__ float bf16bits_to_f32(unsigned short u) {
    return __uint_as_float(((unsigned int)u) << 16);
}

__device__ __forceinline__ ushort4 cvt4(float4 v) {
    ushort4 o;
    o.x = f32_to_bf16bits(v.x); o.y = f32_to_bf16bits(v.y);
    o.z = f32_to_bf16bits(v.z); o.w = f32_to_bf16bits(v.w);
    return o;
}

// ------- transpose img (cam,C,H,W) f32 -> (cam,H,W,C) bf16 for coalesced gathers
__global__ __launch_bounds__(256) void k_transpose(const float* __restrict__ img,
                                                   unsigned short* __restrict__ imgt) {
    int tid = blockIdx.x * 256 + threadIdx.x;
    if (tid >= NCAM*CIMG*HF*WF) return;
    int c = tid % CIMG;
    int r = tid / CIMG;
    int x = r % WF;
    int r2 = r / WF;
    int y = r2 % HF;
    int cam = r2 / HF;
    imgt[tid] = f32_to_bf16bits(img[((cam*CIMG + c)*HF + y)*WF + x]);
}

// ------- projection + bilinear setup + grid scatter ---------------------------
__global__ __launch_bounds__(256) void k_proj(const int* __restrict__ vc,
                                              const float* __restrict__ l2i,
                                              const float* __restrict__ iaug,
                                              const float* __restrict__ laug,
                                              int* __restrict__ grid,
                                              unsigned int* __restrict__ meta,
                                              uint2* __restrict__ wts) {
    int i = blockIdx.x * 256 + threadIdx.x;
    if (i >= MPTS) return;
    int cz = vc[i*4+1], cy = vc[i*4+2], cx = vc[i*4+3];
    atomicMax(&grid[(cz*GYD + cy)*GXD + cx], i);
    float cxf = (float)cx, cyf = (float)cy, czf = (float)cz;
    float a00=laug[0],a01=laug[1],a02=laug[2];
    float a10=laug[4],a11=laug[5],a12=laug[6];
    float a20=laug[8],a21=laug[9],a22=laug[10];
    float t0=laug[3], t1=laug[7], t2=laug[11];
    float det = a00*(a11*a22-a12*a21) - a01*(a10*a22-a12*a20) + a02*(a10*a21-a11*a20);
    float id = 1.0f/det;
    float b00 =  (a11*a22-a12*a21)*id, b01 = -(a01*a22-a02*a21)*id, b02 =  (a01*a12-a02*a11)*id;
    float b10 = -(a10*a22-a12*a20)*id, b11 =  (a00*a22-a02*a20)*id, b12 = -(a00*a12-a02*a10)*id;
    float b20 =  (a10*a21-a11*a20)*id, b21 = -(a00*a21-a01*a20)*id, b22 =  (a00*a11-a01*a10)*id;
    float px = cxf-t0, py = cyf-t1, pz = czf-t2;
    float X = b00*px + b01*py + b02*pz;
    float Y = b10*px + b11*py + b12*pz;
    float Z = b20*px + b21*py + b22*pz;
    #pragma unroll
    for (int cam = 0; cam < NCAM; cam++) {
        const float* Lm = l2i + cam*16;
        float c0 = Lm[0]*X + Lm[1]*Y + Lm[2]*Z  + Lm[3];
        float c1 = Lm[4]*X + Lm[5]*Y + Lm[6]*Z  + Lm[7];
        float c2 = Lm[8]*X + Lm[9]*Y + Lm[10]*Z + Lm[11];
        float z  = fminf(fmaxf(c2, 1e-5f), 100000.0f);
        float vx = c0/z, vy = c1/z, vz = z;
        const float* Am = iaug + cam*16;
        float d0 = Am[0]*vx + Am[1]*vy + Am[2]*vz + Am[3];
        float d1 = Am[4]*vx + Am[5]*vy + Am[6]*vz + Am[7];
        float x = d0 * ((float)(WF-1)/(float)ORIW);
        float y = d1 * ((float)(HF-1)/(float)ORIH);
        bool act = (x > -1.0f) && (x < (float)WF) && (y > -1.0f) && (y < (float)HF);
        float x0f = floorf(x), y0f = floorf(y);
        int x0 = (int)x0f, y0 = (int)y0f;
        float wx1 = x - x0f, wy1 = y - y0f;
        float wx0 = 1.f - wx1, wy0 = 1.f - wy1;
        float ux0, ux1, uy0, uy1;
        if (x0 < 0)            { ux0 = wx1; ux1 = 0.f; }
        else if (x0 >= WF-1)   { ux0 = 0.f; ux1 = wx0; }
        else                   { ux0 = wx0; ux1 = wx1; }
        if (y0 < 0)            { uy0 = wy1; uy1 = 0.f; }
        else if (y0 >= HF-1)   { uy0 = 0.f; uy1 = wy0; }
        else                   { uy0 = wy0; uy1 = wy1; }
        int xb = min(max(x0, 0), WF-2);
        int yb = min(max(y0, 0), HF-2);
        unsigned int m = 0u;
        __half2 h01 = __floats2half2_rn(0.f, 0.f), h23 = h01;
        if (act) {
            m = 0x8000u | (unsigned int)(yb*WF + xb);
            h01 = __floats2half2_rn(ux0*uy0, ux1*uy0);
            h23 = __floats2half2_rn(ux0*uy1, ux1*uy1);
        }
        meta[i*6 + cam] = m;
        uint2 wv;
        wv.x = *reinterpret_cast<unsigned int*>(&h01);
        wv.y = *reinterpret_cast<unsigned int*>(&h23);
        wts[i*6 + cam] = wv;
    }
}

// ------- fuse pts half: stream pts f32 -> bf16 into fuse rows ----------------
__global__ __launch_bounds__(256) void k_fuse_pts(const float4* __restrict__ pts4,
                                                  ushort4* __restrict__ fuse4) {
    int t = blockIdx.x*256 + threadIdx.x;        // t over M*8
    int i = t >> 3, c = t & 7;
    float4 v0 = pts4[i*32 + c];
    float4 v1 = pts4[i*32 + c + 8];
    float4 v2 = pts4[i*32 + c + 16];
    float4 v3 = pts4[i*32 + c + 24];
    fuse4[i*56 + c]      = cvt4(v0);
    fuse4[i*56 + c + 8]  = cvt4(v1);
    fuse4[i*56 + c + 16] = cvt4(v2);
    fuse4[i*56 + c + 24] = cvt4(v3);
}

// ------- fuse img half: bilinear gather from bf16 imgt, 8 channels/thread -----
__global__ __launch_bounds__(256) void k_fuse_img(const uint4* __restrict__ imgt16,
                                                  const unsigned int* __restrict__ meta,
                                                  const uint2* __restrict__ wts,
                                                  uint4* __restrict__ fuse16o) {
    int t = blockIdx.x*256 + threadIdx.x;        // t over M*12
    int i = t / 12, sg = t % 12;
    unsigned int m[NCAM]; uint2 w[NCAM];
    #pragma unroll
    for (int cam = 0; cam < NCAM; cam++) { m[cam] = meta[i*6+cam]; w[cam] = wts[i*6+cam]; }
    float acc[8] = {0.f,0.f,0.f,0.f,0.f,0.f,0.f,0.f};
    #pragma unroll
    for (int cam = 0; cam < NCAM; cam++) {
        if (m[cam] & 0x8000u) {
            int pix = (int)(m[cam] & 0x1FFFu);
            const uint4* base = imgt16 + (size_t)cam*(HF*WF*(CIMG/8)) + (size_t)pix*(CIMG/8) + sg;
            uint4 t00 = base[0];
            uint4 t01 = base[(CIMG/8)];
            uint4 t10 = base[WF*(CIMG/8)];
            uint4 t11 = base[(WF+1)*(CIMG/8)];
            float2 w01 = __half22float2(*reinterpret_cast<const __half2*>(&w[cam].x));
            float2 w23 = __half22float2(*reinterpret_cast<const __half2*>(&w[cam].y));
            const unsigned short* s00 = reinterpret_cast<const unsigned short*>(&t00);
            const unsigned short* s01 = reinterpret_cast<const unsigned short*>(&t01);
            const unsigned short* s10 = reinterpret_cast<const unsigned short*>(&t10);
            const unsigned short* s11 = reinterpret_cast<const unsigned short*>(&t11);
            #pragma unroll
            for (int ch = 0; ch < 8; ch++) {
                acc[ch] += bf16bits_to_f32(s00[ch])*w01.x + bf16bits_to_f32(s01[ch])*w01.y
                         + bf16bits_to_f32(s10[ch])*w23.x + bf16bits_to_f32(s11[ch])*w23.y;
            }
        }
    }
    unsigned int o0 = (unsigned int)f32_to_bf16bits(acc[0]) | ((unsigned int)f32_to_bf16bits(acc[1]) << 16);
    unsigned int o1 = (unsigned int)f32_to_bf16bits(acc[2]) | ((unsigned int)f32_to_bf16bits(acc[3]) << 16);
    unsigned int o2 = (unsigned int)f32_to_bf16bits(acc[4]) | ((unsigned int)f32_to_bf16bits(acc[5]) << 16);
    unsigned int o3 = (unsigned int)f32_to_bf16bits(acc[6]) | ((unsigned int)f32_to_bf16bits(acc[7]) << 16);
    fuse16o[(size_t)i*28 + 16 + sg] = make_uint4(o0, o1, o2, o3);
}

// ---------------- pack conv_w into bf16 MFMA B-fragment layout ----------------
__global__ __launch_bounds__(256) void k_wpack(const float* __restrict__ conv,
                                               ushort4* __restrict__ wp) {
    int tid = blockIdx.x * 256 + threadIdx.x;
    if (tid >= 27*7*8*64) return;
    int lane = tid & 63;
    int nt   = (tid >> 6) & 7;
    int kk   = (tid >> 9) % 7;
    int k27  = tid / 3584;
    int n     = nt*16 + (lane & 15);
    int kbase = kk*32 + (lane >> 4)*8;
    const float* src = conv + ((size_t)k27*FDIM + kbase)*PDIM + n;
    ushort4 lo, hi;
    lo.x = f32_to_bf16bits(src[0*PDIM]);
    lo.y = f32_to_bf16bits(src[1*PDIM]);
    lo.z = f32_to_bf16bits(src[2*PDIM]);
    lo.w = f32_to_bf16bits(src[3*PDIM]);
    hi.x = f32_to_bf16bits(src[4*PDIM]);
    hi.y = f32_to_bf16bits(src[5*PDIM]);
    hi.z = f32_to_bf16bits(src[6*PDIM]);
    hi.w = f32_to_bf16bits(src[7*PDIM]);
    wp[tid*2]   = lo;
    wp[tid*2+1] = hi;
}

// ===== unified conv: per 64-point tile, loop 27 offsets, masked MFMA, =========
// ===== accumulate in registers across all k, BN+ReLU, single pure store ======
__global__ __launch_bounds__(256) void k_conv(const int4* __restrict__ vc4,
                                              const int* __restrict__ grid,
                                              const uint4* __restrict__ fuse16,
                                              const bf16x8* __restrict__ wpb,
                                              const float* __restrict__ gamma,
                                              const float* __restrict__ beta,
                                              const float* __restrict__ mean,
                                              const float* __restrict__ var,
                                              float* __restrict__ out) {
    int i0 = blockIdx.x * TROWS;
    int tid = threadIdx.x;

    __shared__ int s_cz[TROWS], s_cy[TROWS], s_cx[TROWS];
    __shared__ int s_j[27][TROWS];
    __shared__ unsigned int s_mask[27];          // bit m: rows [m*16,m*16+16) have a valid id
    __shared__ unsigned short s_fb[TROWS][FDIM_P];

    if (tid < TROWS) {
        int4 v = vc4[i0 + tid];
        s_cz[tid] = v.y; s_cy[tid] = v.z; s_cx[tid] = v.w;
    }
    __syncthreads();

    // prefetch all 27x64 grid lookups (one latency round)
    for (int idx = tid; idx < 27*TROWS; idx += 256) {
        int k = idx >> 6, r = idx & 63;
        int dz = k/9 - 1, dy = (k/3)%3 - 1, dx = k%3 - 1;
        int nz = s_cz[r]+dz, ny = s_cy[r]+dy, nx = s_cx[r]+dx;
        int id = -1;
        if (nz >= 0 && nz < GZD && ny >= 0 && ny < GYD && nx >= 0 && nx < GXD)
            id = grid[(nz*GYD + ny)*GXD + nx];
        s_j[k][r] = id;
    }
    __syncthreads();
    if (tid < 27) {
        unsigned int m = 0;
        #pragma unroll 8
        for (int r = 0; r < TROWS; r++)
            if (s_j[tid][r] >= 0) m |= 1u << (r >> 4);
        s_mask[tid] = m;
    }
    __syncthreads();

    int lane = tid & 63, wv = tid >> 6;
    int quad = lane >> 4, l15 = lane & 15;
    // precompute fill (row,col) pairs: 7 iterations cover 64*28 uint4 slots
    int fr[7], fc[7];
    #pragma unroll
    for (int it = 0; it < 7; it++) {
        int idx = it*256 + tid;
        fr[it] = idx / 28; fc[it] = idx % 28;
    }

    f32x4 acc[4][2] = {};

    for (int k = 0; k < 27; k++) {
        unsigned int msk = s_mask[k];
        if (msk == 0) continue;                   // block-uniform

        // preload this k's 14 B-fragments (L2-resident wpack), overlap with fill
        bf16x8 b[7][2];
        #pragma unroll
        for (int kk = 0; kk < 7; kk++) {
            b[kk][0] = wpb[(((k*7 + kk)*8) + wv*2 + 0)*64 + lane];
            b[kk][1] = wpb[(((k*7 + kk)*8) + wv*2 + 1)*64 + lane];
        }

        // fill only active 16-row subtiles (zeros for invalid rows within them)
        #pragma unroll
        for (int it = 0; it < 7; it++) {
            int r = fr[it], c = fc[it];
            if ((msk >> (r >> 4)) & 1u) {
                int j = s_j[k][r];
                uint4 v = make_uint4(0u, 0u, 0u, 0u);
                if (j >= 0) v = fuse16[(size_t)j*28 + c];
                *reinterpret_cast<uint4*>(&s_fb[r][c*8]) = v;
            }
        }
        __syncthreads();

        #pragma unroll
        for (int mt = 0; mt < 4; mt++) {
            if ((msk >> mt) & 1u) {
                #pragma unroll
                for (int kk = 0; kk < 7; kk++) {
                    bf16x8 a = *reinterpret_cast<const bf16x8*>(&s_fb[mt*16 + l15][kk*32 + quad*8]);
                    acc[mt][0] = __builtin_amdgcn_mfma_f32_16x16x32_bf16(a, b[kk][0], acc[mt][0], 0, 0, 0);
                    acc[mt][1] = __builtin_amdgcn_mfma_f32_16x16x32_bf16(a, b[kk][1], acc[mt][1], 0, 0, 0);
                }
            }
        }
        __syncthreads();                          // s_fb reused next k
    }

    // BN + ReLU epilogue, pure store
    #pragma unroll
    for (int nt = 0; nt < 2; nt++) {
        int col = wv*32 + nt*16 + l15;
        float g  = gamma[col], bb = beta[col], mn = mean[col];
        float rs = rsqrtf(var[col] + BN_EPS);
        #pragma unroll
        for (int mt = 0; mt < 4; mt++) {
            #pragma unroll
            for (int r = 0; r < 4; r++) {
                int row = mt*16 + quad*4 + r;
                float v = acc[mt][nt][r];
                v = (v - mn)*rs*g + bb;
                out[(size_t)(i0 + row)*PDIM + col] = fmaxf(v, 0.f);
            }
        }
    }
}

extern "C" void kernel_launch(void* const* d_in, const int* in_sizes, int n_in,
                              void* d_out, int out_size, void* d_ws, size_t ws_size,
                              hipStream_t stream) {
    const float* pts   = (const float*)d_in[0];
    const int*   vc    = (const int*)d_in[1];
    const float* img   = (const float*)d_in[2];
    const float* l2i   = (const float*)d_in[3];
    const float* iaug  = (const float*)d_in[4];
    const float* laug  = (const float*)d_in[5];
    const float* conv  = (const float*)d_in[6];
    const float* gamma = (const float*)d_in[7];
    const float* beta  = (const float*)d_in[8];
    const float* mean  = (const float*)d_in[9];
    const float* var   = (const float*)d_in[10];
    float* out = (float*)d_out;

    char* ws = (char*)d_ws;
    int*            grid  = (int*)(ws + OFF_GRID);
    unsigned short* imgt  = (unsigned short*)(ws + OFF_IMGT);
    unsigned int*   descm = (unsigned int*)(ws + OFF_DESCM);
    uint2*          descw = (uint2*)(ws + OFF_DESCW);
    ushort4*        wp    = (ushort4*)(ws + OFF_WPACK);   // overlays descm AFTER k_fuse_img
    ushort4*        fuse4 = (ushort4*)(ws + OFF_FUSE);
    const uint4*    fuse16 = (const uint4*)fuse4;
    uint4*          fuse16o = (uint4*)fuse4;
    const bf16x8*   wpb    = (const bf16x8*)wp;

    hipMemsetAsync(grid, 0xFF, (size_t)NCELLS*4, stream);

    int blocksM = (MPTS + 255)/256;
    k_transpose<<<(NCAM*CIMG*HF*WF + 255)/256, 256, 0, stream>>>(img, imgt);
    k_proj<<<blocksM, 256, 0, stream>>>(vc, l2i, iaug, laug, grid, descm, descw);
    k_fuse_pts<<<BPTS, 256, 0, stream>>>((const float4*)pts, fuse4);
    k_fuse_img<<<BIMG, 256, 0, stream>>>((const uint4*)imgt, descm, descw, fuse16o);
    k_wpack<<<(27*7*8*64 + 255)/256, 256, 0, stream>>>(conv, wp);   // after k_fuse_img (descm overlay)
    k_conv<<<MPTS/TROWS, 256, 0, stream>>>((const int4*)vc, grid, fuse16, wpb,
                                           gamma, beta, mean, var, out);
}

// Round 8
// 492.902 us; speedup vs baseline: 1.0888x; 1.0588x over previous
//
#include <hip/hip_runtime.h>
#include <hip/hip_bf16.h>
#include <hip/hip_fp16.h>

#define MPTS 200000
#define NCAM 6
#define CIMG 96
#define HF 32
#define WF 88
#define PDIM 128
#define FDIM 224
#define FDIM_P 232            // LDS row pad: dword stride 116 ≡ 20 (mod 32) → 2-way max (free)
#define ORIH 256
#define ORIW 704
#define GZD 32
#define GYD 512
#define GXD 448
#define NCELLS (GZD*GYD*GXD)
#define PAIR_CAP 16384
#define BN_EPS 1e-5f
#define TROWS 64              // GEMM tile rows (pairs/points per block)

// ---- workspace layout (bytes), all offsets 16B-aligned, no overlays ----
#define OFF_GRID   0UL            // int[NCELLS]            29,360,128 B
#define OFF_IMGT   29360128UL     // bf16[6*32*88*96]        3,244,032 B
#define OFF_DESCM  32604160UL     // uint[M*6]               4,800,000 B
#define OFF_DESCW  37404160UL     // uint2[M*6]              9,600,000 B
#define OFF_WPACK  47004160UL     // bf16 frags              1,548,288 B  (own region now)
#define OFF_FUSE   48552448UL     // bf16[M*224]            89,600,000 B
#define OFF_CNT    138152448UL    // int[32]
#define OFF_PAIRS  138152576UL    // int2[27*PAIR_CAP]       3,538,944 B
// total 141,691,520 B  (ws_size >= 263 MB proven in round 5)

// ---- k_prep block partition (all sections independent) ----
#define B_GRIDCLR 1792            // 1792*256 thr * 64 B = 29,360,128 B exact
#define B_OUTCLR  6250            // 6250*256 thr * 64 B = 102,400,000 B exact (M*128 f32)
#define B_CNTCLR  1
#define B_TRANS   6336            // 6336*256 = 1,622,016 exact
#define B_WPACK   378             // 378*256 = 96,768 exact (27*7*8*64)
#define B_FPTS    6250            // M*8 threads
#define P0 (B_GRIDCLR)
#define P1 (P0 + B_OUTCLR)
#define P2 (P1 + B_CNTCLR)
#define P3 (P2 + B_TRANS)
#define P4 (P3 + B_WPACK)
#define B_PREP (P4 + B_FPTS)

// ---- k_samp block partition ----
#define B_FIMG  9375              // M*12 threads
#define B_PAIRS 782               // ceil(M/256)
#define B_SAMP (B_FIMG + B_PAIRS)

typedef __attribute__((ext_vector_type(8))) short bf16x8;
typedef __attribute__((ext_vector_type(4))) float f32x4;

__device__ __forceinline__ unsigned short f32_to_bf16bits(float f) {
    __hip_bfloat16 h = __float2bfloat16(f);   // RNE
    return *reinterpret_cast<unsigned short*>(&h);
}

__device__ __forceinline__ float bf16bits_to_f32(unsigned short u) {
    return __uint_as_float(((unsigned int)u) << 16);
}

__device__ __forceinline__ ushort4 cvt4(float4 v) {
    ushort4 o;
    o.x = f32_to_bf16bits(v.x); o.y = f32_to_bf16bits(v.y);
    o.z = f32_to_bf16bits(v.z); o.w = f32_to_bf16bits(v.w);
    return o;
}

// ===== launch 1: all independent prep (clears + transpose + wpack + fuse_pts) =
__global__ __launch_bounds__(256) void k_prep(const float* __restrict__ img,
                                              unsigned short* __restrict__ imgt,
                                              const float* __restrict__ conv,
                                              ushort4* __restrict__ wp,
                                              const float4* __restrict__ pts4,
                                              ushort4* __restrict__ fuse4,
                                              uint4* __restrict__ grid4,
                                              float4* __restrict__ out4,
                                              int* __restrict__ cnt) {
    int b = blockIdx.x, tid = threadIdx.x;
    if (b < P0) {
        // grid = 0xFF (64 B/thread)
        uint4 v = make_uint4(~0u, ~0u, ~0u, ~0u);
        uint4* p = grid4 + (size_t)(b*256 + tid)*4;
        p[0] = v; p[1] = v; p[2] = v; p[3] = v;
    } else if (b < P1) {
        // out = 0 (64 B/thread)
        int t = (b - P0)*256 + tid;
        float4 z = make_float4(0.f, 0.f, 0.f, 0.f);
        float4* p = out4 + (size_t)t*4;
        p[0] = z; p[1] = z; p[2] = z; p[3] = z;
    } else if (b < P2) {
        if (tid < 32) cnt[tid] = 0;
    } else if (b < P3) {
        // transpose img (cam,C,H,W) f32 -> (cam,H,W,C) bf16
        int t = (b - P2)*256 + tid;
        int c = t % CIMG;
        int r = t / CIMG;
        int x = r % WF;
        int r2 = r / WF;
        int y = r2 % HF;
        int cam = r2 / HF;
        imgt[t] = f32_to_bf16bits(img[((cam*CIMG + c)*HF + y)*WF + x]);
    } else if (b < P4) {
        // pack conv_w into bf16 MFMA B-fragment layout
        int t = (b - P3)*256 + tid;
        int lane = t & 63;
        int nt   = (t >> 6) & 7;
        int kk   = (t >> 9) % 7;
        int k27  = t / 3584;
        int n     = nt*16 + (lane & 15);
        int kbase = kk*32 + (lane >> 4)*8;
        const float* src = conv + ((size_t)k27*FDIM + kbase)*PDIM + n;
        ushort4 lo, hi;
        lo.x = f32_to_bf16bits(src[0*PDIM]);
        lo.y = f32_to_bf16bits(src[1*PDIM]);
        lo.z = f32_to_bf16bits(src[2*PDIM]);
        lo.w = f32_to_bf16bits(src[3*PDIM]);
        hi.x = f32_to_bf16bits(src[4*PDIM]);
        hi.y = f32_to_bf16bits(src[5*PDIM]);
        hi.z = f32_to_bf16bits(src[6*PDIM]);
        hi.w = f32_to_bf16bits(src[7*PDIM]);
        wp[t*2]   = lo;
        wp[t*2+1] = hi;
    } else {
        // pts f32 -> bf16 fuse rows (4 independent float4 streams/thread)
        int t = (b - P4)*256 + tid;              // t over M*8
        int i = t >> 3, c = t & 7;
        float4 v0 = pts4[i*32 + c];
        float4 v1 = pts4[i*32 + c + 8];
        float4 v2 = pts4[i*32 + c + 16];
        float4 v3 = pts4[i*32 + c + 24];
        fuse4[i*56 + c]      = cvt4(v0);
        fuse4[i*56 + c + 8]  = cvt4(v1);
        fuse4[i*56 + c + 16] = cvt4(v2);
        fuse4[i*56 + c + 24] = cvt4(v3);
    }
}

// ===== launch 2: projection + bilinear setup + grid scatter ===================
__global__ __launch_bounds__(256) void k_proj(const int* __restrict__ vc,
                                              const float* __restrict__ l2i,
                                              const float* __restrict__ iaug,
                                              const float* __restrict__ laug,
                                              int* __restrict__ grid,
                                              unsigned int* __restrict__ meta,
                                              uint2* __restrict__ wts) {
    int i = blockIdx.x * 256 + threadIdx.x;
    if (i >= MPTS) return;
    int cz = vc[i*4+1], cy = vc[i*4+2], cx = vc[i*4+3];
    atomicMax(&grid[(cz*GYD + cy)*GXD + cx], i);
    float cxf = (float)cx, cyf = (float)cy, czf = (float)cz;
    float a00=laug[0],a01=laug[1],a02=laug[2];
    float a10=laug[4],a11=laug[5],a12=laug[6];
    float a20=laug[8],a21=laug[9],a22=laug[10];
    float t0=laug[3], t1=laug[7], t2=laug[11];
    float det = a00*(a11*a22-a12*a21) - a01*(a10*a22-a12*a20) + a02*(a10*a21-a11*a20);
    float id = 1.0f/det;
    float b00 =  (a11*a22-a12*a21)*id, b01 = -(a01*a22-a02*a21)*id, b02 =  (a01*a12-a02*a11)*id;
    float b10 = -(a10*a22-a12*a20)*id, b11 =  (a00*a22-a02*a20)*id, b12 = -(a00*a12-a02*a10)*id;
    float b20 =  (a10*a21-a11*a20)*id, b21 = -(a00*a21-a01*a20)*id, b22 =  (a00*a11-a01*a10)*id;
    float px = cxf-t0, py = cyf-t1, pz = czf-t2;
    float X = b00*px + b01*py + b02*pz;
    float Y = b10*px + b11*py + b12*pz;
    float Z = b20*px + b21*py + b22*pz;
    #pragma unroll
    for (int cam = 0; cam < NCAM; cam++) {
        const float* Lm = l2i + cam*16;
        float c0 = Lm[0]*X + Lm[1]*Y + Lm[2]*Z  + Lm[3];
        float c1 = Lm[4]*X + Lm[5]*Y + Lm[6]*Z  + Lm[7];
        float c2 = Lm[8]*X + Lm[9]*Y + Lm[10]*Z + Lm[11];
        float z  = fminf(fmaxf(c2, 1e-5f), 100000.0f);
        float vx = c0/z, vy = c1/z, vz = z;
        const float* Am = iaug + cam*16;
        float d0 = Am[0]*vx + Am[1]*vy + Am[2]*vz + Am[3];
        float d1 = Am[4]*vx + Am[5]*vy + Am[6]*vz + Am[7];
        float x = d0 * ((float)(WF-1)/(float)ORIW);
        float y = d1 * ((float)(HF-1)/(float)ORIH);
        bool act = (x > -1.0f) && (x < (float)WF) && (y > -1.0f) && (y < (float)HF);
        float x0f = floorf(x), y0f = floorf(y);
        int x0 = (int)x0f, y0 = (int)y0f;
        float wx1 = x - x0f, wy1 = y - y0f;
        float wx0 = 1.f - wx1, wy0 = 1.f - wy1;
        float ux0, ux1, uy0, uy1;
        if (x0 < 0)            { ux0 = wx1; ux1 = 0.f; }
        else if (x0 >= WF-1)   { ux0 = 0.f; ux1 = wx0; }
        else                   { ux0 = wx0; ux1 = wx1; }
        if (y0 < 0)            { uy0 = wy1; uy1 = 0.f; }
        else if (y0 >= HF-1)   { uy0 = 0.f; uy1 = wy0; }
        else                   { uy0 = wy0; uy1 = wy1; }
        int xb = min(max(x0, 0), WF-2);
        int yb = min(max(y0, 0), HF-2);
        unsigned int m = 0u;
        __half2 h01 = __floats2half2_rn(0.f, 0.f), h23 = h01;
        if (act) {
            m = 0x8000u | (unsigned int)(yb*WF + xb);
            h01 = __floats2half2_rn(ux0*uy0, ux1*uy0);
            h23 = __floats2half2_rn(ux0*uy1, ux1*uy1);
        }
        meta[i*6 + cam] = m;
        uint2 wv;
        wv.x = *reinterpret_cast<unsigned int*>(&h01);
        wv.y = *reinterpret_cast<unsigned int*>(&h23);
        wts[i*6 + cam] = wv;
    }
}

// ===== launch 3: img bilinear sampling + pair-list build (independent halves) =
__global__ __launch_bounds__(256) void k_samp(const uint4* __restrict__ imgt16,
                                              const unsigned int* __restrict__ meta,
                                              const uint2* __restrict__ wts,
                                              uint4* __restrict__ fuse16o,
                                              const int* __restrict__ vc,
                                              const int* __restrict__ grid,
                                              int* __restrict__ cnt,
                                              int2* __restrict__ pairs) {
    __shared__ int s_wcnt[4][27];
    __shared__ int s_wbase[4][27];
    int b = blockIdx.x, tid = threadIdx.x;
    if (b < B_FIMG) {
        int t = b*256 + tid;                     // t over M*12
        int i = t / 12, sg = t % 12;
        unsigned int m[NCAM]; uint2 w[NCAM];
        #pragma unroll
        for (int cam = 0; cam < NCAM; cam++) { m[cam] = meta[i*6+cam]; w[cam] = wts[i*6+cam]; }
        float acc[8] = {0.f,0.f,0.f,0.f,0.f,0.f,0.f,0.f};
        #pragma unroll
        for (int cam = 0; cam < NCAM; cam++) {
            if (m[cam] & 0x8000u) {
                int pix = (int)(m[cam] & 0x1FFFu);
                const uint4* base = imgt16 + (size_t)cam*(HF*WF*(CIMG/8)) + (size_t)pix*(CIMG/8) + sg;
                uint4 t00 = base[0];
                uint4 t01 = base[(CIMG/8)];
                uint4 t10 = base[WF*(CIMG/8)];
                uint4 t11 = base[(WF+1)*(CIMG/8)];
                float2 w01 = __half22float2(*reinterpret_cast<const __half2*>(&w[cam].x));
                float2 w23 = __half22float2(*reinterpret_cast<const __half2*>(&w[cam].y));
                const unsigned short* s00 = reinterpret_cast<const unsigned short*>(&t00);
                const unsigned short* s01 = reinterpret_cast<const unsigned short*>(&t01);
                const unsigned short* s10 = reinterpret_cast<const unsigned short*>(&t10);
                const unsigned short* s11 = reinterpret_cast<const unsigned short*>(&t11);
                #pragma unroll
                for (int ch = 0; ch < 8; ch++) {
                    acc[ch] += bf16bits_to_f32(s00[ch])*w01.x + bf16bits_to_f32(s01[ch])*w01.y
                             + bf16bits_to_f32(s10[ch])*w23.x + bf16bits_to_f32(s11[ch])*w23.y;
                }
            }
        }
        unsigned int o0 = (unsigned int)f32_to_bf16bits(acc[0]) | ((unsigned int)f32_to_bf16bits(acc[1]) << 16);
        unsigned int o1 = (unsigned int)f32_to_bf16bits(acc[2]) | ((unsigned int)f32_to_bf16bits(acc[3]) << 16);
        unsigned int o2 = (unsigned int)f32_to_bf16bits(acc[4]) | ((unsigned int)f32_to_bf16bits(acc[5]) << 16);
        unsigned int o3 = (unsigned int)f32_to_bf16bits(acc[6]) | ((unsigned int)f32_to_bf16bits(acc[7]) << 16);
        fuse16o[(size_t)i*28 + 16 + sg] = make_uint4(o0, o1, o2, o3);
    } else {
        int i = (b - B_FIMG)*256 + tid;
        bool act = (i < MPTS);
        int cz = 0, cy = 0, cx = 0;
        if (act) { cz = vc[i*4+1]; cy = vc[i*4+2]; cx = vc[i*4+3]; }
        int wv = tid >> 6, ln = tid & 63;
        int nid[27];
        int rnk[27];
        #pragma unroll
        for (int k = 0; k < 27; k++) {
            if (k == 13) continue;
            int dz = k/9 - 1, dy = (k/3)%3 - 1, dx = k%3 - 1;
            int nz = cz+dz, ny = cy+dy, nx = cx+dx;
            int id = -1;
            if (act && nz >= 0 && nz < GZD && ny >= 0 && ny < GYD && nx >= 0 && nx < GXD)
                id = grid[(nz*GYD + ny)*GXD + nx];
            nid[k] = id;
            unsigned long long mm = __ballot(id >= 0);
            if (ln == 0) s_wcnt[wv][k] = __popcll(mm);
            rnk[k] = __popcll(mm & ((1ull << ln) - 1ull));
        }
        __syncthreads();
        if (tid < 27 && tid != 13) {
            int k = tid;
            int c0 = s_wcnt[0][k], c1 = s_wcnt[1][k], c2 = s_wcnt[2][k], c3 = s_wcnt[3][k];
            int tot = c0 + c1 + c2 + c3;
            int bse = (tot > 0) ? atomicAdd(&cnt[k], tot) : 0;
            s_wbase[0][k] = bse;
            s_wbase[1][k] = bse + c0;
            s_wbase[2][k] = bse + c0 + c1;
            s_wbase[3][k] = bse + c0 + c1 + c2;
        }
        __syncthreads();
        #pragma unroll
        for (int k = 0; k < 27; k++) {
            if (k == 13) continue;
            if (nid[k] >= 0) {
                int slot = s_wbase[wv][k] + rnk[k];
                if (slot < PAIR_CAP) pairs[k*PAIR_CAP + slot] = make_int2(i, nid[k]);
            }
        }
    }
}

// ---- MFMA micro-kernel pieces (64-row tiles) --------------------------------
__device__ __forceinline__ void fill_tile64(unsigned short (*s_fb)[FDIM_P],
                                            const int* s_j,
                                            const uint4* __restrict__ fuse16,
                                            int tid) {
    #pragma unroll
    for (int it = 0; it < (TROWS*28)/256; it++) {
        int idx = it*256 + tid;
        int r = idx / 28, c = idx % 28;
        int j = s_j[r];
        uint4 v = make_uint4(0u, 0u, 0u, 0u);
        if (j >= 0) v = fuse16[(size_t)j*28 + c];
        *reinterpret_cast<uint4*>(&s_fb[r][c*8]) = v;
    }
}

__device__ __forceinline__ void gemm_mfma64(const unsigned short (*s_fb)[FDIM_P],
                                            const bf16x8* __restrict__ wpb,
                                            int k27, int lane, int wv,
                                            f32x4 acc[4][2]) {
    int quad = lane >> 4, l15 = lane & 15;
    bf16x8 b[7][2];
    #pragma unroll
    for (int kk = 0; kk < 7; kk++) {
        b[kk][0] = wpb[(((k27*7 + kk)*8) + wv*2 + 0)*64 + lane];
        b[kk][1] = wpb[(((k27*7 + kk)*8) + wv*2 + 1)*64 + lane];
    }
    #pragma unroll
    for (int kk = 0; kk < 7; kk++) {
        #pragma unroll
        for (int mt = 0; mt < 4; mt++) {
            bf16x8 a = *reinterpret_cast<const bf16x8*>(&s_fb[mt*16 + l15][kk*32 + quad*8]);
            acc[mt][0] = __builtin_amdgcn_mfma_f32_16x16x32_bf16(a, b[kk][0], acc[mt][0], 0, 0, 0);
            acc[mt][1] = __builtin_amdgcn_mfma_f32_16x16x32_bf16(a, b[kk][1], acc[mt][1], 0, 0, 0);
        }
    }
}

// ===== launch 4: neighbor GEMMs, atomic scatter-add ==========================
__global__ __launch_bounds__(256) void k_nbr(const int2* __restrict__ pairs,
                                             const int* __restrict__ cnt,
                                             const uint4* __restrict__ fuse16,
                                             const bf16x8* __restrict__ wpb,
                                             float* __restrict__ out) {
    int k = blockIdx.y;
    if (k >= 13) k += 1;
    int n = cnt[k];
    if (n > PAIR_CAP) n = PAIR_CAP;
    int p0 = blockIdx.x * TROWS;
    if (p0 >= n) return;
    int nn = min(TROWS, n - p0);

    __shared__ int s_i[TROWS];
    __shared__ int s_j[TROWS];
    __shared__ unsigned short s_fb[TROWS][FDIM_P];
    int tid = threadIdx.x;
    if (tid < TROWS) {
        if (tid < nn) { int2 pr = pairs[k*PAIR_CAP + p0 + tid]; s_i[tid] = pr.x; s_j[tid] = pr.y; }
        else          { s_i[tid] = -1; s_j[tid] = -1; }
    }
    __syncthreads();
    fill_tile64(s_fb, s_j, fuse16, tid);
    __syncthreads();

    int lane = tid & 63, wv = tid >> 6;
    int quad = lane >> 4, l15 = lane & 15;
    f32x4 acc[4][2] = {};
    gemm_mfma64(s_fb, wpb, k, lane, wv, acc);

    #pragma unroll
    for (int nt = 0; nt < 2; nt++) {
        int col = wv*32 + nt*16 + l15;
        #pragma unroll
        for (int mt = 0; mt < 4; mt++) {
            #pragma unroll
            for (int r = 0; r < 4; r++) {
                int row = mt*16 + quad*4 + r;
                int ii = s_i[row];
                if (ii >= 0) unsafeAtomicAdd(&out[(size_t)ii*PDIM + col], acc[mt][nt][r]);
            }
        }
    }
}

// ===== launch 5: center GEMM (k=13) + BN + ReLU epilogue =====================
__global__ __launch_bounds__(256) void k_center(const int* __restrict__ vc,
                                                const int* __restrict__ grid,
                                                const uint4* __restrict__ fuse16,
                                                const bf16x8* __restrict__ wpb,
                                                const float* __restrict__ gamma,
                                                const float* __restrict__ beta,
                                                const float* __restrict__ mean,
                                                const float* __restrict__ var,
                                                float* __restrict__ out) {
    int i0 = blockIdx.x * TROWS;
    __shared__ int s_j[TROWS];
    __shared__ unsigned short s_fb[TROWS][FDIM_P];
    int tid = threadIdx.x;
    if (tid < TROWS) {
        int i = i0 + tid;
        int cz = vc[i*4+1], cy = vc[i*4+2], cx = vc[i*4+3];
        s_j[tid] = grid[(cz*GYD + cy)*GXD + cx];
    }
    __syncthreads();
    fill_tile64(s_fb, s_j, fuse16, tid);
    __syncthreads();

    int lane = tid & 63, wv = tid >> 6;
    int quad = lane >> 4, l15 = lane & 15;
    f32x4 acc[4][2] = {};
    gemm_mfma64(s_fb, wpb, 13, lane, wv, acc);

    #pragma unroll
    for (int nt = 0; nt < 2; nt++) {
        int col = wv*32 + nt*16 + l15;
        float g  = gamma[col], bb = beta[col], mn = mean[col];
        float rs = rsqrtf(var[col] + BN_EPS);
        #pragma unroll
        for (int mt = 0; mt < 4; mt++) {
            #pragma unroll
            for (int r = 0; r < 4; r++) {
                int row = mt*16 + quad*4 + r;
                size_t o = (size_t)(i0 + row)*PDIM + col;
                float v = out[o] + acc[mt][nt][r];
                v = (v - mn)*rs*g + bb;
                out[o] = fmaxf(v, 0.f);
            }
        }
    }
}

extern "C" void kernel_launch(void* const* d_in, const int* in_sizes, int n_in,
                              void* d_out, int out_size, void* d_ws, size_t ws_size,
                              hipStream_t stream) {
    const float* pts   = (const float*)d_in[0];
    const int*   vc    = (const int*)d_in[1];
    const float* img   = (const float*)d_in[2];
    const float* l2i   = (const float*)d_in[3];
    const float* iaug  = (const float*)d_in[4];
    const float* laug  = (const float*)d_in[5];
    const float* conv  = (const float*)d_in[6];
    const float* gamma = (const float*)d_in[7];
    const float* beta  = (const float*)d_in[8];
    const float* mean  = (const float*)d_in[9];
    const float* var   = (const float*)d_in[10];
    float* out = (float*)d_out;

    char* ws = (char*)d_ws;
    int*            grid  = (int*)(ws + OFF_GRID);
    unsigned short* imgt  = (unsigned short*)(ws + OFF_IMGT);
    unsigned int*   descm = (unsigned int*)(ws + OFF_DESCM);
    uint2*          descw = (uint2*)(ws + OFF_DESCW);
    ushort4*        wp    = (ushort4*)(ws + OFF_WPACK);
    ushort4*        fuse4 = (ushort4*)(ws + OFF_FUSE);
    int*            cnt   = (int*)(ws + OFF_CNT);
    int2*           pairs = (int2*)(ws + OFF_PAIRS);
    const uint4*    fuse16 = (const uint4*)fuse4;
    uint4*          fuse16o = (uint4*)fuse4;
    const bf16x8*   wpb    = (const bf16x8*)wp;

    // 5 dispatches total (was 10): clears folded into k_prep, independent
    // kernels merged, no hipMemsetAsync.
    k_prep<<<B_PREP, 256, 0, stream>>>(img, imgt, conv, wp, (const float4*)pts,
                                       fuse4, (uint4*)grid, (float4*)out, cnt);
    k_proj<<<(MPTS + 255)/256, 256, 0, stream>>>(vc, l2i, iaug, laug, grid, descm, descw);
    k_samp<<<B_SAMP, 256, 0, stream>>>((const uint4*)imgt, descm, descw, fuse16o,
                                       vc, grid, cnt, pairs);
    k_nbr<<<dim3(PAIR_CAP/TROWS, 26), 256, 0, stream>>>(pairs, cnt, fuse16, wpb, out);
    k_center<<<MPTS/TROWS, 256, 0, stream>>>(vc, grid, fuse16, wpb,
                                             gamma, beta, mean, var, out);
}

// Round 9
// 474.316 us; speedup vs baseline: 1.1315x; 1.0392x over previous
//
#include <hip/hip_runtime.h>
#include <hip/hip_bf16.h>
#include <hip/hip_fp16.h>

#define MPTS 200000
#define NCAM 6
#define CIMG 96
#define HF 32
#define WF 88
#define PDIM 128
#define FDIM 224
#define FDIM_P 232            // LDS row pad: dword stride 116 ≡ 20 (mod 32) → 2-way max (free)
#define ORIH 256
#define ORIW 704
#define GZD 32
#define GYD 512
#define GXD 448
#define NCELLS (GZD*GYD*GXD)
#define PAIR_CAP 16384
#define BN_EPS 1e-5f
#define TROWS 64              // GEMM tile rows (pairs/points per block)

// ---- workspace layout (bytes), all offsets 16B-aligned, no overlays ----
#define OFF_GRID   0UL            // int[NCELLS]            29,360,128 B
#define OFF_IMGT   29360128UL     // bf16[6*32*88*96]        3,244,032 B
#define OFF_DESCM  32604160UL     // uint[M*6]               4,800,000 B
#define OFF_DESCW  37404160UL     // uint2[M*6]              9,600,000 B
#define OFF_WPACK  47004160UL     // bf16 frags              1,548,288 B
#define OFF_FUSE   48552448UL     // bf16[M*224]            89,600,000 B
#define OFF_CNT    138152448UL    // int[32]
#define OFF_PAIRS  138152576UL    // int2[27*PAIR_CAP]       3,538,944 B
// total 141,691,520 B

// ---- k_prep block partition (all sections independent) ----
#define B_GRIDCLR 1792            // 1792 blk * 1024 uint4 = 29,360,128 B exact
#define B_OUTCLR  6250            // 6250 blk * 1024 float4 = 102,400,000 B exact
#define B_CNTCLR  1
#define B_TRANS   6336            // 6336*256 = 1,622,016 exact
#define B_WPACK   378             // 378*256 = 96,768 exact (27*7*8*64)
#define B_FPTS    6250            // M*8 threads
#define P0 (B_GRIDCLR)
#define P1 (P0 + B_OUTCLR)
#define P2 (P1 + B_CNTCLR)
#define P3 (P2 + B_TRANS)
#define P4 (P3 + B_WPACK)
#define B_PREP (P4 + B_FPTS)

// ---- k_samp block partition ----
#define B_FIMG  9375              // M*12 threads
#define B_PAIRS 782               // ceil(M/256)
#define B_SAMP (B_FIMG + B_PAIRS)

typedef __attribute__((ext_vector_type(8))) short bf16x8;
typedef __attribute__((ext_vector_type(4))) float f32x4;

__device__ __forceinline__ unsigned short f32_to_bf16bits(float f) {
    __hip_bfloat16 h = __float2bfloat16(f);   // RNE
    return *reinterpret_cast<unsigned short*>(&h);
}

__device__ __forceinline__ float bf16bits_to_f32(unsigned short u) {
    return __uint_as_float(((unsigned int)u) << 16);
}

__device__ __forceinline__ ushort4 cvt4(float4 v) {
    ushort4 o;
    o.x = f32_to_bf16bits(v.x); o.y = f32_to_bf16bits(v.y);
    o.z = f32_to_bf16bits(v.z); o.w = f32_to_bf16bits(v.w);
    return o;
}

// ===== launch 1: all independent prep (clears + transpose + wpack + fuse_pts) =
// Clears are lane-contiguous per store instruction (full-line coalescing):
// index [k*256 + tid], NOT [tid*4 + k] (the latter = 64B-stride partial-line writes).
__global__ __launch_bounds__(256) void k_prep(const float* __restrict__ img,
                                              unsigned short* __restrict__ imgt,
                                              const float* __restrict__ conv,
                                              ushort4* __restrict__ wp,
                                              const float4* __restrict__ pts4,
                                              ushort4* __restrict__ fuse4,
                                              uint4* __restrict__ grid4,
                                              float4* __restrict__ out4,
                                              int* __restrict__ cnt) {
    int b = blockIdx.x, tid = threadIdx.x;
    if (b < P0) {
        // grid = 0xFF, 1024 uint4/block, coalesced
        uint4 v = make_uint4(~0u, ~0u, ~0u, ~0u);
        uint4* p = grid4 + (size_t)b*1024;
        #pragma unroll
        for (int k = 0; k < 4; k++) p[k*256 + tid] = v;
    } else if (b < P1) {
        // out = 0, 1024 float4/block, coalesced
        float4 z = make_float4(0.f, 0.f, 0.f, 0.f);
        float4* p = out4 + (size_t)(b - P0)*1024;
        #pragma unroll
        for (int k = 0; k < 4; k++) p[k*256 + tid] = z;
    } else if (b < P2) {
        if (tid < 32) cnt[tid] = 0;
    } else if (b < P3) {
        // transpose img (cam,C,H,W) f32 -> (cam,H,W,C) bf16
        int t = (b - P2)*256 + tid;
        int c = t % CIMG;
        int r = t / CIMG;
        int x = r % WF;
        int r2 = r / WF;
        int y = r2 % HF;
        int cam = r2 / HF;
        imgt[t] = f32_to_bf16bits(img[((cam*CIMG + c)*HF + y)*WF + x]);
    } else if (b < P4) {
        // pack conv_w into bf16 MFMA B-fragment layout
        int t = (b - P3)*256 + tid;
        int lane = t & 63;
        int nt   = (t >> 6) & 7;
        int kk   = (t >> 9) % 7;
        int k27  = t / 3584;
        int n     = nt*16 + (lane & 15);
        int kbase = kk*32 + (lane >> 4)*8;
        const float* src = conv + ((size_t)k27*FDIM + kbase)*PDIM + n;
        ushort4 lo, hi;
        lo.x = f32_to_bf16bits(src[0*PDIM]);
        lo.y = f32_to_bf16bits(src[1*PDIM]);
        lo.z = f32_to_bf16bits(src[2*PDIM]);
        lo.w = f32_to_bf16bits(src[3*PDIM]);
        hi.x = f32_to_bf16bits(src[4*PDIM]);
        hi.y = f32_to_bf16bits(src[5*PDIM]);
        hi.z = f32_to_bf16bits(src[6*PDIM]);
        hi.w = f32_to_bf16bits(src[7*PDIM]);
        wp[t*2]   = lo;
        wp[t*2+1] = hi;
    } else {
        // pts f32 -> bf16 fuse rows (4 independent float4 streams/thread)
        int t = (b - P4)*256 + tid;              // t over M*8
        int i = t >> 3, c = t & 7;
        float4 v0 = pts4[i*32 + c];
        float4 v1 = pts4[i*32 + c + 8];
        float4 v2 = pts4[i*32 + c + 16];
        float4 v3 = pts4[i*32 + c + 24];
        fuse4[i*56 + c]      = cvt4(v0);
        fuse4[i*56 + c + 8]  = cvt4(v1);
        fuse4[i*56 + c + 16] = cvt4(v2);
        fuse4[i*56 + c + 24] = cvt4(v3);
    }
}

// ===== launch 2: projection + bilinear setup + grid scatter ===================
__global__ __launch_bounds__(256) void k_proj(const int* __restrict__ vc,
                                              const float* __restrict__ l2i,
                                              const float* __restrict__ iaug,
                                              const float* __restrict__ laug,
                                              int* __restrict__ grid,
                                              unsigned int* __restrict__ meta,
                                              uint2* __restrict__ wts) {
    int i = blockIdx.x * 256 + threadIdx.x;
    if (i >= MPTS) return;
    int cz = vc[i*4+1], cy = vc[i*4+2], cx = vc[i*4+3];
    atomicMax(&grid[(cz*GYD + cy)*GXD + cx], i);
    float cxf = (float)cx, cyf = (float)cy, czf = (float)cz;
    float a00=laug[0],a01=laug[1],a02=laug[2];
    float a10=laug[4],a11=laug[5],a12=laug[6];
    float a20=laug[8],a21=laug[9],a22=laug[10];
    float t0=laug[3], t1=laug[7], t2=laug[11];
    float det = a00*(a11*a22-a12*a21) - a01*(a10*a22-a12*a20) + a02*(a10*a21-a11*a20);
    float id = 1.0f/det;
    float b00 =  (a11*a22-a12*a21)*id, b01 = -(a01*a22-a02*a21)*id, b02 =  (a01*a12-a02*a11)*id;
    float b10 = -(a10*a22-a12*a20)*id, b11 =  (a00*a22-a02*a20)*id, b12 = -(a00*a12-a02*a10)*id;
    float b20 =  (a10*a21-a11*a20)*id, b21 = -(a00*a21-a01*a20)*id, b22 =  (a00*a11-a01*a10)*id;
    float px = cxf-t0, py = cyf-t1, pz = czf-t2;
    float X = b00*px + b01*py + b02*pz;
    float Y = b10*px + b11*py + b12*pz;
    float Z = b20*px + b21*py + b22*pz;
    #pragma unroll
    for (int cam = 0; cam < NCAM; cam++) {
        const float* Lm = l2i + cam*16;
        float c0 = Lm[0]*X + Lm[1]*Y + Lm[2]*Z  + Lm[3];
        float c1 = Lm[4]*X + Lm[5]*Y + Lm[6]*Z  + Lm[7];
        float c2 = Lm[8]*X + Lm[9]*Y + Lm[10]*Z + Lm[11];
        float z  = fminf(fmaxf(c2, 1e-5f), 100000.0f);
        float vx = c0/z, vy = c1/z, vz = z;
        const float* Am = iaug + cam*16;
        float d0 = Am[0]*vx + Am[1]*vy + Am[2]*vz + Am[3];
        float d1 = Am[4]*vx + Am[5]*vy + Am[6]*vz + Am[7];
        float x = d0 * ((float)(WF-1)/(float)ORIW);
        float y = d1 * ((float)(HF-1)/(float)ORIH);
        bool act = (x > -1.0f) && (x < (float)WF) && (y > -1.0f) && (y < (float)HF);
        float x0f = floorf(x), y0f = floorf(y);
        int x0 = (int)x0f, y0 = (int)y0f;
        float wx1 = x - x0f, wy1 = y - y0f;
        float wx0 = 1.f - wx1, wy0 = 1.f - wy1;
        float ux0, ux1, uy0, uy1;
        if (x0 < 0)            { ux0 = wx1; ux1 = 0.f; }
        else if (x0 >= WF-1)   { ux0 = 0.f; ux1 = wx0; }
        else                   { ux0 = wx0; ux1 = wx1; }
        if (y0 < 0)            { uy0 = wy1; uy1 = 0.f; }
        else if (y0 >= HF-1)   { uy0 = 0.f; uy1 = wy0; }
        else                   { uy0 = wy0; uy1 = wy1; }
        int xb = min(max(x0, 0), WF-2);
        int yb = min(max(y0, 0), HF-2);
        unsigned int m = 0u;
        __half2 h01 = __floats2half2_rn(0.f, 0.f), h23 = h01;
        if (act) {
            m = 0x8000u | (unsigned int)(yb*WF + xb);
            h01 = __floats2half2_rn(ux0*uy0, ux1*uy0);
            h23 = __floats2half2_rn(ux0*uy1, ux1*uy1);
        }
        meta[i*6 + cam] = m;
        uint2 wv;
        wv.x = *reinterpret_cast<unsigned int*>(&h01);
        wv.y = *reinterpret_cast<unsigned int*>(&h23);
        wts[i*6 + cam] = wv;
    }
}

// ===== launch 3: img bilinear sampling + pair-list build (independent halves) =
__global__ __launch_bounds__(256) void k_samp(const uint4* __restrict__ imgt16,
                                              const unsigned int* __restrict__ meta,
                                              const uint2* __restrict__ wts,
                                              uint4* __restrict__ fuse16o,
                                              const int* __restrict__ vc,
                                              const int* __restrict__ grid,
                                              int* __restrict__ cnt,
                                              int2* __restrict__ pairs) {
    __shared__ int s_wcnt[4][27];
    __shared__ int s_wbase[4][27];
    int b = blockIdx.x, tid = threadIdx.x;
    if (b < B_FIMG) {
        int t = b*256 + tid;                     // t over M*12
        int i = t / 12, sg = t % 12;
        unsigned int m[NCAM]; uint2 w[NCAM];
        #pragma unroll
        for (int cam = 0; cam < NCAM; cam++) { m[cam] = meta[i*6+cam]; w[cam] = wts[i*6+cam]; }
        float acc[8] = {0.f,0.f,0.f,0.f,0.f,0.f,0.f,0.f};
        #pragma unroll
        for (int cam = 0; cam < NCAM; cam++) {
            if (m[cam] & 0x8000u) {
                int pix = (int)(m[cam] & 0x1FFFu);
                const uint4* base = imgt16 + (size_t)cam*(HF*WF*(CIMG/8)) + (size_t)pix*(CIMG/8) + sg;
                uint4 t00 = base[0];
                uint4 t01 = base[(CIMG/8)];
                uint4 t10 = base[WF*(CIMG/8)];
                uint4 t11 = base[(WF+1)*(CIMG/8)];
                float2 w01 = __half22float2(*reinterpret_cast<const __half2*>(&w[cam].x));
                float2 w23 = __half22float2(*reinterpret_cast<const __half2*>(&w[cam].y));
                const unsigned short* s00 = reinterpret_cast<const unsigned short*>(&t00);
                const unsigned short* s01 = reinterpret_cast<const unsigned short*>(&t01);
                const unsigned short* s10 = reinterpret_cast<const unsigned short*>(&t10);
                const unsigned short* s11 = reinterpret_cast<const unsigned short*>(&t11);
                #pragma unroll
                for (int ch = 0; ch < 8; ch++) {
                    acc[ch] += bf16bits_to_f32(s00[ch])*w01.x + bf16bits_to_f32(s01[ch])*w01.y
                             + bf16bits_to_f32(s10[ch])*w23.x + bf16bits_to_f32(s11[ch])*w23.y;
                }
            }
        }
        unsigned int o0 = (unsigned int)f32_to_bf16bits(acc[0]) | ((unsigned int)f32_to_bf16bits(acc[1]) << 16);
        unsigned int o1 = (unsigned int)f32_to_bf16bits(acc[2]) | ((unsigned int)f32_to_bf16bits(acc[3]) << 16);
        unsigned int o2 = (unsigned int)f32_to_bf16bits(acc[4]) | ((unsigned int)f32_to_bf16bits(acc[5]) << 16);
        unsigned int o3 = (unsigned int)f32_to_bf16bits(acc[6]) | ((unsigned int)f32_to_bf16bits(acc[7]) << 16);
        fuse16o[(size_t)i*28 + 16 + sg] = make_uint4(o0, o1, o2, o3);
    } else {
        int i = (b - B_FIMG)*256 + tid;
        bool act = (i < MPTS);
        int cz = 0, cy = 0, cx = 0;
        if (act) { cz = vc[i*4+1]; cy = vc[i*4+2]; cx = vc[i*4+3]; }
        int wv = tid >> 6, ln = tid & 63;
        int nid[27];
        int rnk[27];
        #pragma unroll
        for (int k = 0; k < 27; k++) {
            if (k == 13) continue;
            int dz = k/9 - 1, dy = (k/3)%3 - 1, dx = k%3 - 1;
            int nz = cz+dz, ny = cy+dy, nx = cx+dx;
            int id = -1;
            if (act && nz >= 0 && nz < GZD && ny >= 0 && ny < GYD && nx >= 0 && nx < GXD)
                id = grid[(nz*GYD + ny)*GXD + nx];
            nid[k] = id;
            unsigned long long mm = __ballot(id >= 0);
            if (ln == 0) s_wcnt[wv][k] = __popcll(mm);
            rnk[k] = __popcll(mm & ((1ull << ln) - 1ull));
        }
        __syncthreads();
        if (tid < 27 && tid != 13) {
            int k = tid;
            int c0 = s_wcnt[0][k], c1 = s_wcnt[1][k], c2 = s_wcnt[2][k], c3 = s_wcnt[3][k];
            int tot = c0 + c1 + c2 + c3;
            int bse = (tot > 0) ? atomicAdd(&cnt[k], tot) : 0;
            s_wbase[0][k] = bse;
            s_wbase[1][k] = bse + c0;
            s_wbase[2][k] = bse + c0 + c1;
            s_wbase[3][k] = bse + c0 + c1 + c2;
        }
        __syncthreads();
        #pragma unroll
        for (int k = 0; k < 27; k++) {
            if (k == 13) continue;
            if (nid[k] >= 0) {
                int slot = s_wbase[wv][k] + rnk[k];
                if (slot < PAIR_CAP) pairs[k*PAIR_CAP + slot] = make_int2(i, nid[k]);
            }
        }
    }
}

// ---- MFMA micro-kernel pieces (64-row tiles) --------------------------------
__device__ __forceinline__ void fill_tile64(unsigned short (*s_fb)[FDIM_P],
                                            const int* s_j,
                                            const uint4* __restrict__ fuse16,
                                            int tid) {
    #pragma unroll
    for (int it = 0; it < (TROWS*28)/256; it++) {
        int idx = it*256 + tid;
        int r = idx / 28, c = idx % 28;
        int j = s_j[r];
        uint4 v = make_uint4(0u, 0u, 0u, 0u);
        if (j >= 0) v = fuse16[(size_t)j*28 + c];
        *reinterpret_cast<uint4*>(&s_fb[r][c*8]) = v;
    }
}

__device__ __forceinline__ void gemm_mfma64(const unsigned short (*s_fb)[FDIM_P],
                                            const bf16x8* __restrict__ wpb,
                                            int k27, int lane, int wv,
                                            f32x4 acc[4][2]) {
    int quad = lane >> 4, l15 = lane & 15;
    bf16x8 b[7][2];
    #pragma unroll
    for (int kk = 0; kk < 7; kk++) {
        b[kk][0] = wpb[(((k27*7 + kk)*8) + wv*2 + 0)*64 + lane];
        b[kk][1] = wpb[(((k27*7 + kk)*8) + wv*2 + 1)*64 + lane];
    }
    #pragma unroll
    for (int kk = 0; kk < 7; kk++) {
        #pragma unroll
        for (int mt = 0; mt < 4; mt++) {
            bf16x8 a = *reinterpret_cast<const bf16x8*>(&s_fb[mt*16 + l15][kk*32 + quad*8]);
            acc[mt][0] = __builtin_amdgcn_mfma_f32_16x16x32_bf16(a, b[kk][0], acc[mt][0], 0, 0, 0);
            acc[mt][1] = __builtin_amdgcn_mfma_f32_16x16x32_bf16(a, b[kk][1], acc[mt][1], 0, 0, 0);
        }
    }
}

// ===== launch 4: neighbor GEMMs, atomic scatter-add ==========================
__global__ __launch_bounds__(256) void k_nbr(const int2* __restrict__ pairs,
                                             const int* __restrict__ cnt,
                                             const uint4* __restrict__ fuse16,
                                             const bf16x8* __restrict__ wpb,
                                             float* __restrict__ out) {
    int k = blockIdx.y;
    if (k >= 13) k += 1;
    int n = cnt[k];
    if (n > PAIR_CAP) n = PAIR_CAP;
    int p0 = blockIdx.x * TROWS;
    if (p0 >= n) return;
    int nn = min(TROWS, n - p0);

    __shared__ int s_i[TROWS];
    __shared__ int s_j[TROWS];
    __shared__ unsigned short s_fb[TROWS][FDIM_P];
    int tid = threadIdx.x;
    if (tid < TROWS) {
        if (tid < nn) { int2 pr = pairs[k*PAIR_CAP + p0 + tid]; s_i[tid] = pr.x; s_j[tid] = pr.y; }
        else          { s_i[tid] = -1; s_j[tid] = -1; }
    }
    __syncthreads();
    fill_tile64(s_fb, s_j, fuse16, tid);
    __syncthreads();

    int lane = tid & 63, wv = tid >> 6;
    int quad = lane >> 4, l15 = lane & 15;
    f32x4 acc[4][2] = {};
    gemm_mfma64(s_fb, wpb, k, lane, wv, acc);

    #pragma unroll
    for (int nt = 0; nt < 2; nt++) {
        int col = wv*32 + nt*16 + l15;
        #pragma unroll
        for (int mt = 0; mt < 4; mt++) {
            #pragma unroll
            for (int r = 0; r < 4; r++) {
                int row = mt*16 + quad*4 + r;
                int ii = s_i[row];
                if (ii >= 0) unsafeAtomicAdd(&out[(size_t)ii*PDIM + col], acc[mt][nt][r]);
            }
        }
    }
}

// ===== launch 5: center GEMM (k=13) + BN + ReLU epilogue =====================
__global__ __launch_bounds__(256) void k_center(const int* __restrict__ vc,
                                                const int* __restrict__ grid,
                                                const uint4* __restrict__ fuse16,
                                                const bf16x8* __restrict__ wpb,
                                                const float* __restrict__ gamma,
                                                const float* __restrict__ beta,
                                                const float* __restrict__ mean,
                                                const float* __restrict__ var,
                                                float* __restrict__ out) {
    int i0 = blockIdx.x * TROWS;
    __shared__ int s_j[TROWS];
    __shared__ unsigned short s_fb[TROWS][FDIM_P];
    int tid = threadIdx.x;
    if (tid < TROWS) {
        int i = i0 + tid;
        int cz = vc[i*4+1], cy = vc[i*4+2], cx = vc[i*4+3];
        s_j[tid] = grid[(cz*GYD + cy)*GXD + cx];
    }
    __syncthreads();
    fill_tile64(s_fb, s_j, fuse16, tid);
    __syncthreads();

    int lane = tid & 63, wv = tid >> 6;
    int quad = lane >> 4, l15 = lane & 15;
    f32x4 acc[4][2] = {};
    gemm_mfma64(s_fb, wpb, 13, lane, wv, acc);

    #pragma unroll
    for (int nt = 0; nt < 2; nt++) {
        int col = wv*32 + nt*16 + l15;
        float g  = gamma[col], bb = beta[col], mn = mean[col];
        float rs = rsqrtf(var[col] + BN_EPS);
        #pragma unroll
        for (int mt = 0; mt < 4; mt++) {
            #pragma unroll
            for (int r = 0; r < 4; r++) {
                int row = mt*16 + quad*4 + r;
                size_t o = (size_t)(i0 + row)*PDIM + col;
                float v = out[o] + acc[mt][nt][r];
                v = (v - mn)*rs*g + bb;
                out[o] = fmaxf(v, 0.f);
            }
        }
    }
}

extern "C" void kernel_launch(void* const* d_in, const int* in_sizes, int n_in,
                              void* d_out, int out_size, void* d_ws, size_t ws_size,
                              hipStream_t stream) {
    const float* pts   = (const float*)d_in[0];
    const int*   vc    = (const int*)d_in[1];
    const float* img   = (const float*)d_in[2];
    const float* l2i   = (const float*)d_in[3];
    const float* iaug  = (const float*)d_in[4];
    const float* laug  = (const float*)d_in[5];
    const float* conv  = (const float*)d_in[6];
    const float* gamma = (const float*)d_in[7];
    const float* beta  = (const float*)d_in[8];
    const float* mean  = (const float*)d_in[9];
    const float* var   = (const float*)d_in[10];
    float* out = (float*)d_out;

    char* ws = (char*)d_ws;
    int*            grid  = (int*)(ws + OFF_GRID);
    unsigned short* imgt  = (unsigned short*)(ws + OFF_IMGT);
    unsigned int*   descm = (unsigned int*)(ws + OFF_DESCM);
    uint2*          descw = (uint2*)(ws + OFF_DESCW);
    ushort4*        wp    = (ushort4*)(ws + OFF_WPACK);
    ushort4*        fuse4 = (ushort4*)(ws + OFF_FUSE);
    int*            cnt   = (int*)(ws + OFF_CNT);
    int2*           pairs = (int2*)(ws + OFF_PAIRS);
    const uint4*    fuse16 = (const uint4*)fuse4;
    uint4*          fuse16o = (uint4*)fuse4;
    const bf16x8*   wpb    = (const bf16x8*)wp;

    k_prep<<<B_PREP, 256, 0, stream>>>(img, imgt, conv, wp, (const float4*)pts,
                                       fuse4, (uint4*)grid, (float4*)out, cnt);
    k_proj<<<(MPTS + 255)/256, 256, 0, stream>>>(vc, l2i, iaug, laug, grid, descm, descw);
    k_samp<<<B_SAMP, 256, 0, stream>>>((const uint4*)imgt, descm, descw, fuse16o,
                                       vc, grid, cnt, pairs);
    k_nbr<<<dim3(PAIR_CAP/TROWS, 26), 256, 0, stream>>>(pairs, cnt, fuse16, wpb, out);
    k_center<<<MPTS/TROWS, 256, 0, stream>>>(vc, grid, fuse16, wpb,
                                             gamma, beta, mean, var, out);
}